// Round 6
// baseline (2155.620 us; speedup 1.0000x reference)
//
#include <hip/hip_runtime.h>
#include <math.h>

#define N0c 500000
#define Rc  100000
#define NDc 50000
#define E0c 2000000
#define E1c 1000000
#define GB0 128            // graphs per set0 bucket
#define NB0 782            // ceil(Rc/GB0)
#define DB1 64             // dst nodes per set1 bucket
#define NB1 782            // ceil(NDc/DB1)
#define NBk (NB0 + NB1)    // 1564
#define PB  489            // partition blocks: ceil(E0c/4096)
#define MTILE 32

__device__ __forceinline__ unsigned f2u(float f) {
    unsigned u = __float_as_uint(f);
    return (u & 0x80000000u) ? ~u : (u | 0x80000000u);
}
__device__ __forceinline__ float u2f(unsigned u) {
    unsigned v = (u & 0x80000000u) ? (u & 0x7fffffffu) : ~u;
    return __uint_as_float(v);
}

// ---------------- coarse histogram (LDS-aggregated) + node counts ----------------
__global__ __launch_bounds__(256) void k_hist_coarse(
        const int* __restrict__ dst0, const int* __restrict__ node_graph,
        const int* __restrict__ dst1, unsigned* __restrict__ cnt,
        unsigned* __restrict__ cntN) {
    __shared__ unsigned h[NBk];
    int tid = threadIdx.x, b = blockIdx.x;
    for (int i = tid; i < NBk; i += 256) h[i] = 0u;
    __syncthreads();
    int base0 = b * 4096, base1 = b * 2048, baseN = b * 1024;
    for (int i = tid; i < 4096; i += 256) {
        int e = base0 + i;
        if (e < E0c) atomicAdd(&h[node_graph[dst0[e]] >> 7], 1u);
    }
    for (int i = tid; i < 2048; i += 256) {
        int e = base1 + i;
        if (e < E1c) atomicAdd(&h[NB0 + (dst1[e] >> 6)], 1u);
    }
    for (int i = tid; i < 1024; i += 256) {
        int n = baseN + i;
        if (n < N0c) atomicAdd(&cntN[node_graph[n]], 1u);
    }
    __syncthreads();
    for (int i = tid; i < NBk; i += 256) {
        unsigned v = h[i];
        if (v) atomicAdd(&cnt[i], v);
    }
}

// ---------------- 3-pass exclusive scan ----------------
__global__ void k_scan1(const unsigned* __restrict__ in, unsigned* __restrict__ out,
                        unsigned* __restrict__ bsum, int n) {
    __shared__ unsigned s[1024];
    int i = blockIdx.x * 1024 + threadIdx.x;
    unsigned v = (i < n) ? in[i] : 0u;
    s[threadIdx.x] = v;
    __syncthreads();
    for (int off = 1; off < 1024; off <<= 1) {
        unsigned t = (threadIdx.x >= off) ? s[threadIdx.x - off] : 0u;
        __syncthreads();
        s[threadIdx.x] += t;
        __syncthreads();
    }
    if (i < n) out[i] = s[threadIdx.x] - v;
    if (threadIdx.x == 1023) bsum[blockIdx.x] = s[1023];
}

__global__ void k_scan2(unsigned* __restrict__ bsum, int nb) {
    __shared__ unsigned s[1024];
    unsigned v = (threadIdx.x < nb) ? bsum[threadIdx.x] : 0u;
    s[threadIdx.x] = v;
    __syncthreads();
    for (int off = 1; off < 1024; off <<= 1) {
        unsigned t = (threadIdx.x >= off) ? s[threadIdx.x - off] : 0u;
        __syncthreads();
        s[threadIdx.x] += t;
        __syncthreads();
    }
    if (threadIdx.x < nb) bsum[threadIdx.x] = s[threadIdx.x] - v;
}

__global__ void k_scan3(unsigned* __restrict__ out, const unsigned* __restrict__ bsum,
                        unsigned* __restrict__ cursor, int n) {
    int i = blockIdx.x * 1024 + threadIdx.x;
    if (i < n) {
        unsigned v = out[i] + bsum[blockIdx.x];
        out[i] = v;
        cursor[i] = v;
    }
}

// ---------------- tiled coarse place: per-tile LDS hist -> range reserve -> scatter ----------------
__global__ __launch_bounds__(256) void k_place_coarse(
        const int* __restrict__ src0, const int* __restrict__ dst0,
        const int* __restrict__ node_graph, const float* __restrict__ norm_n,
        const float* __restrict__ norm_e, const int* __restrict__ src1,
        const int* __restrict__ dst1, unsigned* __restrict__ gcur,
        int4* __restrict__ coarse0, int2* __restrict__ coarse1) {
    __shared__ unsigned hc[NBk];
    __shared__ unsigned hb[NBk];
    int tid = threadIdx.x, b = blockIdx.x;
    for (int i = tid; i < NBk; i += 256) hc[i] = 0u;
    __syncthreads();
    int base0 = b * 4096, base1 = b * 2048;
    for (int i = tid; i < 4096; i += 256) {
        int e = base0 + i;
        if (e < E0c) atomicAdd(&hc[node_graph[dst0[e]] >> 7], 1u);
    }
    for (int i = tid; i < 2048; i += 256) {
        int e = base1 + i;
        if (e < E1c) atomicAdd(&hc[NB0 + (dst1[e] >> 6)], 1u);
    }
    __syncthreads();
    for (int i = tid; i < NBk; i += 256) {
        unsigned c = hc[i];
        hb[i] = c ? atomicAdd(&gcur[i], c) : 0u;
    }
    __syncthreads();
    for (int i = tid; i < NBk; i += 256) hc[i] = 0u;
    __syncthreads();
    for (int i = tid; i < 4096; i += 256) {
        int e = base0 + i;
        if (e < E0c) {
            int s = src0[e], d = dst0[e];
            int g = node_graph[d];
            float coef = norm_n[s] * norm_n[d] * norm_e[e];
            unsigned bk = g >> 7;
            unsigned r = atomicAdd(&hc[bk], 1u);
            coarse0[hb[bk] + r] = make_int4(s, g, __float_as_int(coef), 0);
        }
    }
    for (int i = tid; i < 2048; i += 256) {
        int e = base1 + i;
        if (e < E1c) {
            int d = dst1[e];
            unsigned bk = NB0 + (d >> 6);
            unsigned r = atomicAdd(&hc[bk], 1u);
            coarse1[hb[bk] + r - (unsigned)E0c] = make_int2(src1[e], d);
        }
    }
}

// ---------------- bucket0: LDS-accumulate x[src]*coef per graph, write r_mean ----------------
__global__ __launch_bounds__(256) void k_bucket0(
        const float* __restrict__ x, const int4* __restrict__ coarse0,
        const unsigned* __restrict__ offs, const unsigned* __restrict__ cntN,
        float* __restrict__ r_mean) {
    int B = blockIdx.x;
    int g0 = B * GB0;
    int ng = min(GB0, Rc - g0);
    __shared__ float acc[GB0 * 65];   // stride 65: bank-skewed per graph row
    int tid = threadIdx.x;
    for (int i = tid; i < GB0 * 65; i += 256) acc[i] = 0.f;
    __syncthreads();
    unsigned beg = offs[B], end = offs[B + 1];   // offs[NB0] == E0c
    int wav = tid >> 6, lane = tid & 63, q = lane >> 4, l = lane & 15;
    for (unsigned base = beg + (unsigned)wav * 4u; base < end; base += 16u) {
        unsigned idx = base + q;
        if (idx < end) {
            int4 p = coarse0[idx];
            float coef = __int_as_float(p.z);
            int gl = p.y - g0;
            float4 v = ((const float4*)(x + (size_t)p.x * 64))[l];
            float* a = &acc[gl * 65 + l * 4];
            atomicAdd(a + 0, v.x * coef);
            atomicAdd(a + 1, v.y * coef);
            atomicAdd(a + 2, v.z * coef);
            atomicAdd(a + 3, v.w * coef);
        }
    }
    __syncthreads();
    for (int j = tid; j < ng * 64; j += 256) {
        int g = j >> 6, col = j & 63;
        r_mean[(size_t)(g0 + g) * 64 + col] = acc[g * 65 + col] / (float)cntN[g0 + g];
    }
}

// ---------------- register-blocked MLP (unchanged from R5) ----------------
__global__ __launch_bounds__(512) void k_mlp(const float* __restrict__ r_in,
                                             const float* __restrict__ W1,
                                             const float* __restrict__ b1,
                                             const float* __restrict__ Wsrc,
                                             const float* __restrict__ bsrc,
                                             const float* __restrict__ attn,
                                             float* __restrict__ feat,
                                             float* __restrict__ score_src, int R) {
    __shared__ float W1s[64 * 64];
    __shared__ float Wss[64 * 128];
    __shared__ float b1s[64], bss[128], atts[128];
    __shared__ float in_s[MTILE * 68];
    __shared__ float t1_s[MTILE * 68];
    int tid = threadIdx.x;
    for (int i = tid; i < 4096; i += 512) W1s[i] = W1[i];
    for (int i = tid; i < 8192; i += 512) Wss[i] = Wsrc[i];
    if (tid < 64) b1s[tid] = b1[tid];
    if (tid >= 64 && tid < 192) bss[tid - 64] = bsrc[tid - 64];
    if (tid >= 192 && tid < 320) atts[tid - 192] = attn[tid - 192];

    int row = tid >> 4, c = tid & 15;
    size_t grow = (size_t)blockIdx.x * MTILE + row;
    float4 vin = ((const float4*)(r_in + grow * 64))[c];
    *((float4*)&in_s[row * 68 + c * 4]) = vin;
    __syncthreads();

    {
        float4 a = {0.f, 0.f, 0.f, 0.f};
        const float* wcol = W1s + c * 4;
        const float* inr = in_s + row * 68;
#pragma unroll
        for (int k = 0; k < 64; k++) {
            float iv = inr[k];
            float4 w = *((const float4*)(wcol + k * 64));
            a.x += iv * w.x; a.y += iv * w.y;
            a.z += iv * w.z; a.w += iv * w.w;
        }
        const float4 bb = *((const float4*)(b1s + c * 4));
        a.x += bb.x; a.y += bb.y; a.z += bb.z; a.w += bb.w;
        a.x = a.x >= 0.f ? a.x : 0.01f * a.x;
        a.y = a.y >= 0.f ? a.y : 0.01f * a.y;
        a.z = a.z >= 0.f ? a.z : 0.01f * a.z;
        a.w = a.w >= 0.f ? a.w : 0.01f * a.w;
        *((float4*)&t1_s[row * 68 + c * 4]) = a;
    }
    __syncthreads();

    {
        float4 a0 = {0.f, 0.f, 0.f, 0.f}, a1 = {0.f, 0.f, 0.f, 0.f};
        const float* w2 = Wss + c * 8;
        const float* t1r = t1_s + row * 68;
#pragma unroll
        for (int k = 0; k < 64; k++) {
            float tv = t1r[k];
            float4 w0 = *((const float4*)(w2 + k * 128));
            float4 w1 = *((const float4*)(w2 + k * 128 + 4));
            a0.x += tv * w0.x; a0.y += tv * w0.y;
            a0.z += tv * w0.z; a0.w += tv * w0.w;
            a1.x += tv * w1.x; a1.y += tv * w1.y;
            a1.z += tv * w1.z; a1.w += tv * w1.w;
        }
        const float4 b0 = *((const float4*)(bss + c * 8));
        const float4 b1v = *((const float4*)(bss + c * 8 + 4));
        a0.x += b0.x; a0.y += b0.y; a0.z += b0.z; a0.w += b0.w;
        a1.x += b1v.x; a1.y += b1v.y; a1.z += b1v.z; a1.w += b1v.w;
        float4* fp = (float4*)(feat + grow * 128 + c * 8);
        fp[0] = a0; fp[1] = a1;
        const float4 at0 = *((const float4*)(atts + c * 8));
        const float4 at1 = *((const float4*)(atts + c * 8 + 4));
        float p =
            (a0.x >= 0.f ? a0.x : 0.2f * a0.x) * at0.x +
            (a0.y >= 0.f ? a0.y : 0.2f * a0.y) * at0.y +
            (a0.z >= 0.f ? a0.z : 0.2f * a0.z) * at0.z +
            (a0.w >= 0.f ? a0.w : 0.2f * a0.w) * at0.w +
            (a1.x >= 0.f ? a1.x : 0.2f * a1.x) * at1.x +
            (a1.y >= 0.f ? a1.y : 0.2f * a1.y) * at1.y +
            (a1.z >= 0.f ? a1.z : 0.2f * a1.z) * at1.z +
            (a1.w >= 0.f ? a1.w : 0.2f * a1.w) * at1.w;
        p += __shfl_xor(p, 1);
        p += __shfl_xor(p, 2);
        if ((c & 3) == 0) score_src[grow * 4 + (c >> 2)] = p;
    }
}

// ---------------- bucket1: fused edge-softmax + weighted sum + head-sum in LDS ----------------
__global__ __launch_bounds__(256) void k_bucket1(
        const float* __restrict__ feat, const float* __restrict__ score,
        const int2* __restrict__ coarse1, const unsigned* __restrict__ offs,
        float* __restrict__ out) {
    int B = blockIdx.x;
    int d0 = B * DB1;
    int nd = min(DB1, NDc - d0);
    __shared__ float acc[DB1 * 130];
    __shared__ unsigned mxu[DB1 * 4];
    __shared__ float sume[DB1 * 4];
    int tid = threadIdx.x;
    for (int i = tid; i < DB1 * 130; i += 256) acc[i] = 0.f;
    mxu[tid] = 0u;     // DB1*4 == 256
    sume[tid] = 0.f;
    __syncthreads();
    unsigned beg = offs[NB0 + B] - (unsigned)E0c;
    unsigned end = (B == NB1 - 1) ? (unsigned)E1c : (offs[NB0 + B + 1] - (unsigned)E0c);
    // pass A: per-(dst,head) max
    for (unsigned i = beg + tid; i < end; i += 256) {
        int2 p = coarse1[i];
        float4 sc = ((const float4*)score)[p.x];
        int dl = p.y - d0;
        atomicMax(&mxu[dl * 4 + 0], f2u(sc.x));
        atomicMax(&mxu[dl * 4 + 1], f2u(sc.y));
        atomicMax(&mxu[dl * 4 + 2], f2u(sc.z));
        atomicMax(&mxu[dl * 4 + 3], f2u(sc.w));
    }
    __syncthreads();
    int wav = tid >> 6, lane = tid & 63, q = lane >> 5, l = lane & 31, h = l >> 3;
    for (unsigned base = beg + (unsigned)wav * 2u; base < end; base += 8u) {
        unsigned idx = base + q;
        if (idx < end) {
            int2 p = coarse1[idx];
            int dl = p.y - d0;
            float sch = score[(size_t)p.x * 4 + h];
            float ex = __expf(sch - u2f(mxu[dl * 4 + h]));
            float4 v = ((const float4*)(feat + (size_t)p.x * 128))[l];
            float* a = &acc[dl * 130 + l * 4];
            atomicAdd(a + 0, v.x * ex);
            atomicAdd(a + 1, v.y * ex);
            atomicAdd(a + 2, v.z * ex);
            atomicAdd(a + 3, v.w * ex);
            if ((l & 7) == 0) atomicAdd(&sume[dl * 4 + h], ex);
        }
    }
    __syncthreads();
    for (int j = tid; j < nd * 32; j += 256) {
        int dl = j >> 5, col = j & 31;
        float o = 0.f;
#pragma unroll
        for (int hh = 0; hh < 4; hh++)
            o += acc[dl * 130 + hh * 32 + col] / sume[dl * 4 + hh];
        out[(size_t)(d0 + dl) * 32 + col] = o;
    }
}

extern "C" void kernel_launch(void* const* d_in, const int* in_sizes, int n_in,
                              void* d_out, int out_size, void* d_ws, size_t ws_size,
                              hipStream_t stream) {
    const float* x      = (const float*)d_in[0];
    const float* norm_n = (const float*)d_in[1];
    const float* norm_e = (const float*)d_in[2];
    const float* W1     = (const float*)d_in[3];
    const float* b1     = (const float*)d_in[4];
    const float* Wsrc   = (const float*)d_in[5];
    const float* bsrc   = (const float*)d_in[6];
    const float* attn   = (const float*)d_in[7];
    const int* src0     = (const int*)d_in[8];
    const int* dst0     = (const int*)d_in[9];
    const int* node_graph = (const int*)d_in[10];
    const int* src1     = (const int*)d_in[11];
    const int* dst1     = (const int*)d_in[12];
    float* out = (float*)d_out;

    char* ws = (char*)d_ws;
    size_t off = 0;
    auto alloc = [&](size_t bytes) { void* p = ws + off; off += bytes; return p; };

    unsigned* cnt  = (unsigned*)alloc(NBk * 4);       // zeroed
    unsigned* cntN = (unsigned*)alloc((size_t)Rc * 4); // zeroed
    size_t zero_bytes = off;
    unsigned* offs = (unsigned*)alloc(NBk * 4);
    unsigned* gcur = (unsigned*)alloc(NBk * 4);
    unsigned* bsum = (unsigned*)alloc(1024 * 4);
    // region A: coarse0 (32 MB) and, later, feat (51.2 MB) — coarse0 dead before k_mlp writes feat
    size_t regionA = (size_t)Rc * 128 * 4;            // 51.2 MB >= E0c*16
    char* pA = (char*)alloc(regionA);
    int4* coarse0 = (int4*)pA;
    float* feat   = (float*)pA;
    int2* coarse1 = (int2*)alloc((size_t)E1c * 8);
    float* r_mean = (float*)alloc((size_t)Rc * 64 * 4);
    float* score_src = (float*)alloc((size_t)Rc * 4 * 4);

    hipMemsetAsync(d_ws, 0, zero_bytes, stream);

    k_hist_coarse<<<PB, 256, 0, stream>>>(dst0, node_graph, dst1, cnt, cntN);
    int nb = (NBk + 1023) / 1024;   // 2
    k_scan1<<<nb, 1024, 0, stream>>>(cnt, offs, bsum, NBk);
    k_scan2<<<1, 1024, 0, stream>>>(bsum, nb);
    k_scan3<<<nb, 1024, 0, stream>>>(offs, bsum, gcur, NBk);

    k_place_coarse<<<PB, 256, 0, stream>>>(src0, dst0, node_graph, norm_n, norm_e,
                                           src1, dst1, gcur, coarse0, coarse1);

    k_bucket0<<<NB0, 256, 0, stream>>>(x, coarse0, offs, cntN, r_mean);
    k_mlp<<<Rc / MTILE, 512, 0, stream>>>(r_mean, W1, b1, Wsrc, bsrc, attn, feat, score_src, Rc);
    k_bucket1<<<NB1, 256, 0, stream>>>(feat, score_src, coarse1, offs, out);
}

// Round 7
// 655.876 us; speedup vs baseline: 3.2866x; 3.2866x over previous
//
#include <hip/hip_runtime.h>
#include <math.h>

#define N0c 500000
#define Rc  100000
#define NDc 50000
#define E0c 2000000
#define E1c 1000000
#define GB0 64                  // graphs per set0 bucket
#define NB0 1563                // ceil(Rc/64)
#define DB1 64                  // dst nodes per set1 bucket
#define NB1 782                 // ceil(NDc/64)
#define NBk (NB0 + NB1)         // 2345
#define T0  8192                // set0 edges per partition tile
#define T1  4096                // set1 edges per partition tile
#define TN  2048                // nodes per partition tile
#define PB  245                 // ceil(E0c/T0); covers E1c/T1 and N0c/TN too
#define CAP 4096                // max edges per bucket (mean ~1280, sd ~36)
#define MTILE 32

// ---------------- coarse histogram (LDS-aggregated) + node counts ----------------
__global__ __launch_bounds__(256) void k_hist_coarse(
        const int* __restrict__ dst0, const int* __restrict__ node_graph,
        const int* __restrict__ dst1, unsigned* __restrict__ cnt,
        unsigned* __restrict__ cntN) {
    __shared__ unsigned h[NBk];
    int tid = threadIdx.x, b = blockIdx.x;
    for (int i = tid; i < NBk; i += 256) h[i] = 0u;
    __syncthreads();
    int base0 = b * T0, base1 = b * T1, baseN = b * TN;
    for (int i = tid; i < T0; i += 256) {
        int e = base0 + i;
        if (e < E0c) atomicAdd(&h[node_graph[dst0[e]] >> 6], 1u);
    }
    for (int i = tid; i < T1; i += 256) {
        int e = base1 + i;
        if (e < E1c) atomicAdd(&h[NB0 + (dst1[e] >> 6)], 1u);
    }
    for (int i = tid; i < TN; i += 256) {
        int n = baseN + i;
        if (n < N0c) atomicAdd(&cntN[node_graph[n]], 1u);
    }
    __syncthreads();
    for (int i = tid; i < NBk; i += 256) {
        unsigned v = h[i];
        if (v) atomicAdd(&cnt[i], v);
    }
}

// ---------------- 3-pass exclusive scan ----------------
__global__ void k_scan1(const unsigned* __restrict__ in, unsigned* __restrict__ out,
                        unsigned* __restrict__ bsum, int n) {
    __shared__ unsigned s[1024];
    int i = blockIdx.x * 1024 + threadIdx.x;
    unsigned v = (i < n) ? in[i] : 0u;
    s[threadIdx.x] = v;
    __syncthreads();
    for (int off = 1; off < 1024; off <<= 1) {
        unsigned t = (threadIdx.x >= off) ? s[threadIdx.x - off] : 0u;
        __syncthreads();
        s[threadIdx.x] += t;
        __syncthreads();
    }
    if (i < n) out[i] = s[threadIdx.x] - v;
    if (threadIdx.x == 1023) bsum[blockIdx.x] = s[1023];
}

__global__ void k_scan2(unsigned* __restrict__ bsum, int nb) {
    __shared__ unsigned s[1024];
    unsigned v = (threadIdx.x < nb) ? bsum[threadIdx.x] : 0u;
    s[threadIdx.x] = v;
    __syncthreads();
    for (int off = 1; off < 1024; off <<= 1) {
        unsigned t = (threadIdx.x >= off) ? s[threadIdx.x - off] : 0u;
        __syncthreads();
        s[threadIdx.x] += t;
        __syncthreads();
    }
    if (threadIdx.x < nb) bsum[threadIdx.x] = s[threadIdx.x] - v;
}

__global__ void k_scan3(unsigned* __restrict__ out, const unsigned* __restrict__ bsum,
                        unsigned* __restrict__ cursor, int n) {
    int i = blockIdx.x * 1024 + threadIdx.x;
    if (i < n) {
        unsigned v = out[i] + bsum[blockIdx.x];
        out[i] = v;
        cursor[i] = v;
    }
}

// ---------------- tiled coarse place: LDS hist -> range reserve -> run-scatter ----------------
// payload0: int2 { src | (g&63)<<19 , coef }   payload1: int { src | (d&63)<<17 }
__global__ __launch_bounds__(256) void k_place_coarse(
        const int* __restrict__ src0, const int* __restrict__ dst0,
        const int* __restrict__ node_graph, const float* __restrict__ norm_n,
        const float* __restrict__ norm_e, const int* __restrict__ src1,
        const int* __restrict__ dst1, unsigned* __restrict__ gcur,
        int2* __restrict__ coarse0, int* __restrict__ coarse1) {
    __shared__ unsigned hc[NBk];
    __shared__ unsigned hb[NBk];
    int tid = threadIdx.x, b = blockIdx.x;
    for (int i = tid; i < NBk; i += 256) hc[i] = 0u;
    __syncthreads();
    int base0 = b * T0, base1 = b * T1;
    for (int i = tid; i < T0; i += 256) {
        int e = base0 + i;
        if (e < E0c) atomicAdd(&hc[node_graph[dst0[e]] >> 6], 1u);
    }
    for (int i = tid; i < T1; i += 256) {
        int e = base1 + i;
        if (e < E1c) atomicAdd(&hc[NB0 + (dst1[e] >> 6)], 1u);
    }
    __syncthreads();
    for (int i = tid; i < NBk; i += 256) {
        unsigned c = hc[i];
        hb[i] = c ? atomicAdd(&gcur[i], c) : 0u;
    }
    __syncthreads();
    for (int i = tid; i < NBk; i += 256) hc[i] = 0u;
    __syncthreads();
    for (int i = tid; i < T0; i += 256) {
        int e = base0 + i;
        if (e < E0c) {
            int s = src0[e], d = dst0[e];
            int g = node_graph[d];
            float coef = norm_n[s] * norm_n[d] * norm_e[e];
            unsigned bk = g >> 6;
            unsigned r = atomicAdd(&hc[bk], 1u);
            coarse0[hb[bk] + r] = make_int2(s | ((g & 63) << 19), __float_as_int(coef));
        }
    }
    for (int i = tid; i < T1; i += 256) {
        int e = base1 + i;
        if (e < E1c) {
            int d = dst1[e];
            unsigned bk = NB0 + (d >> 6);
            unsigned r = atomicAdd(&hc[bk], 1u);
            coarse1[hb[bk] + r - (unsigned)E0c] = src1[e] | ((d & 63) << 17);
        }
    }
}

// ---------------- bucket0: LDS counting sort -> per-wave register gather-reduce ----------------
__global__ __launch_bounds__(256) void k_bucket0(
        const float* __restrict__ x, const int2* __restrict__ coarse0,
        const unsigned* __restrict__ offs, const unsigned* __restrict__ cntN,
        float* __restrict__ r_mean) {
    __shared__ unsigned cur_s[GB0];
    __shared__ unsigned off_s[GB0 + 1];
    __shared__ unsigned short eidx[CAP];
    int B = blockIdx.x, tid = threadIdx.x;
    int g0 = B * GB0;
    int ng = min(GB0, Rc - g0);
    unsigned beg = offs[B], end = offs[B + 1];     // offs[NB0] == E0c
    int n = (int)(end - beg);
    if (n > CAP) n = CAP;
    if (tid < GB0) cur_s[tid] = 0u;
    __syncthreads();
    // counts
    for (int i = tid; i < n; i += 256) {
        int gl = (coarse0[beg + i].x >> 19) & 63;
        atomicAdd(&cur_s[gl], 1u);
    }
    __syncthreads();
    // serial 64-bin exclusive scan
    if (tid == 0) {
        unsigned a = 0;
        for (int i = 0; i < GB0; i++) { unsigned c = cur_s[i]; off_s[i] = a; a += c; }
        off_s[GB0] = a;
    }
    __syncthreads();
    if (tid < GB0) cur_s[tid] = off_s[tid];
    __syncthreads();
    // place local indices
    for (int i = tid; i < n; i += 256) {
        int gl = (coarse0[beg + i].x >> 19) & 63;
        unsigned slot = atomicAdd(&cur_s[gl], 1u);
        eidx[slot] = (unsigned short)i;
    }
    __syncthreads();
    // per-wave gather: wave handles graphs wav, wav+4, ...
    int wav = tid >> 6, lane = tid & 63, q = lane >> 4, l = lane & 15;
    for (int g = wav; g < ng; g += 4) {
        int rbeg = (int)off_s[g], rend = (int)off_s[g + 1];
        float4 acc = {0.f, 0.f, 0.f, 0.f};
        for (int base = rbeg; base < rend; base += 64) {
            int m = min(64, rend - base);
            int s = 0;
            float c = 0.f;
            if (lane < m) {
                int2 p = coarse0[beg + eidx[base + lane]];
                s = p.x & 0x7FFFF;
                c = __int_as_float(p.y);
            }
            int rounds = (m + 3) >> 2;
            for (int t = 0; t < rounds; t++) {
                int idx = 4 * t + q;             // idx >= m broadcasts (0,0) -> adds 0
                int sj = __shfl(s, idx);
                float cj = __shfl(c, idx);
                float4 v = ((const float4*)(x + (size_t)sj * 64))[l];
                acc.x += v.x * cj; acc.y += v.y * cj;
                acc.z += v.z * cj; acc.w += v.w * cj;
            }
        }
        acc.x += __shfl_xor(acc.x, 16); acc.y += __shfl_xor(acc.y, 16);
        acc.z += __shfl_xor(acc.z, 16); acc.w += __shfl_xor(acc.w, 16);
        acc.x += __shfl_xor(acc.x, 32); acc.y += __shfl_xor(acc.y, 32);
        acc.z += __shfl_xor(acc.z, 32); acc.w += __shfl_xor(acc.w, 32);
        if (q == 0) {
            float inv = 1.f / (float)cntN[g0 + g];
            float4 o = {acc.x * inv, acc.y * inv, acc.z * inv, acc.w * inv};
            ((float4*)(r_mean + (size_t)(g0 + g) * 64))[l] = o;
        }
    }
}

// ---------------- register-blocked MLP (unchanged from R5) ----------------
__global__ __launch_bounds__(512) void k_mlp(const float* __restrict__ r_in,
                                             const float* __restrict__ W1,
                                             const float* __restrict__ b1,
                                             const float* __restrict__ Wsrc,
                                             const float* __restrict__ bsrc,
                                             const float* __restrict__ attn,
                                             float* __restrict__ feat,
                                             float* __restrict__ score_src, int R) {
    __shared__ float W1s[64 * 64];
    __shared__ float Wss[64 * 128];
    __shared__ float b1s[64], bss[128], atts[128];
    __shared__ float in_s[MTILE * 68];
    __shared__ float t1_s[MTILE * 68];
    int tid = threadIdx.x;
    for (int i = tid; i < 4096; i += 512) W1s[i] = W1[i];
    for (int i = tid; i < 8192; i += 512) Wss[i] = Wsrc[i];
    if (tid < 64) b1s[tid] = b1[tid];
    if (tid >= 64 && tid < 192) bss[tid - 64] = bsrc[tid - 64];
    if (tid >= 192 && tid < 320) atts[tid - 192] = attn[tid - 192];

    int row = tid >> 4, c = tid & 15;
    size_t grow = (size_t)blockIdx.x * MTILE + row;
    float4 vin = ((const float4*)(r_in + grow * 64))[c];
    *((float4*)&in_s[row * 68 + c * 4]) = vin;
    __syncthreads();

    {
        float4 a = {0.f, 0.f, 0.f, 0.f};
        const float* wcol = W1s + c * 4;
        const float* inr = in_s + row * 68;
#pragma unroll
        for (int k = 0; k < 64; k++) {
            float iv = inr[k];
            float4 w = *((const float4*)(wcol + k * 64));
            a.x += iv * w.x; a.y += iv * w.y;
            a.z += iv * w.z; a.w += iv * w.w;
        }
        const float4 bb = *((const float4*)(b1s + c * 4));
        a.x += bb.x; a.y += bb.y; a.z += bb.z; a.w += bb.w;
        a.x = a.x >= 0.f ? a.x : 0.01f * a.x;
        a.y = a.y >= 0.f ? a.y : 0.01f * a.y;
        a.z = a.z >= 0.f ? a.z : 0.01f * a.z;
        a.w = a.w >= 0.f ? a.w : 0.01f * a.w;
        *((float4*)&t1_s[row * 68 + c * 4]) = a;
    }
    __syncthreads();

    {
        float4 a0 = {0.f, 0.f, 0.f, 0.f}, a1 = {0.f, 0.f, 0.f, 0.f};
        const float* w2 = Wss + c * 8;
        const float* t1r = t1_s + row * 68;
#pragma unroll
        for (int k = 0; k < 64; k++) {
            float tv = t1r[k];
            float4 w0 = *((const float4*)(w2 + k * 128));
            float4 w1 = *((const float4*)(w2 + k * 128 + 4));
            a0.x += tv * w0.x; a0.y += tv * w0.y;
            a0.z += tv * w0.z; a0.w += tv * w0.w;
            a1.x += tv * w1.x; a1.y += tv * w1.y;
            a1.z += tv * w1.z; a1.w += tv * w1.w;
        }
        const float4 b0 = *((const float4*)(bss + c * 8));
        const float4 b1v = *((const float4*)(bss + c * 8 + 4));
        a0.x += b0.x; a0.y += b0.y; a0.z += b0.z; a0.w += b0.w;
        a1.x += b1v.x; a1.y += b1v.y; a1.z += b1v.z; a1.w += b1v.w;
        float4* fp = (float4*)(feat + grow * 128 + c * 8);
        fp[0] = a0; fp[1] = a1;
        const float4 at0 = *((const float4*)(atts + c * 8));
        const float4 at1 = *((const float4*)(atts + c * 8 + 4));
        float p =
            (a0.x >= 0.f ? a0.x : 0.2f * a0.x) * at0.x +
            (a0.y >= 0.f ? a0.y : 0.2f * a0.y) * at0.y +
            (a0.z >= 0.f ? a0.z : 0.2f * a0.z) * at0.z +
            (a0.w >= 0.f ? a0.w : 0.2f * a0.w) * at0.w +
            (a1.x >= 0.f ? a1.x : 0.2f * a1.x) * at1.x +
            (a1.y >= 0.f ? a1.y : 0.2f * a1.y) * at1.y +
            (a1.z >= 0.f ? a1.z : 0.2f * a1.z) * at1.z +
            (a1.w >= 0.f ? a1.w : 0.2f * a1.w) * at1.w;
        p += __shfl_xor(p, 1);
        p += __shfl_xor(p, 2);
        if ((c & 3) == 0) score_src[grow * 4 + (c >> 2)] = p;
    }
}

// ---------------- bucket1: LDS counting sort -> per-wave softmax gather (R5 inner) ----------------
__global__ __launch_bounds__(256) void k_bucket1(
        const float* __restrict__ feat, const float* __restrict__ score,
        const int* __restrict__ coarse1, const unsigned* __restrict__ offs,
        float* __restrict__ out) {
    __shared__ unsigned cur_s[DB1];
    __shared__ unsigned off_s[DB1 + 1];
    __shared__ unsigned short eidx[CAP];
    int B = blockIdx.x, tid = threadIdx.x;
    int d0 = B * DB1;
    int nd = min(DB1, NDc - d0);
    unsigned beg = offs[NB0 + B] - (unsigned)E0c;
    unsigned end = (B == NB1 - 1) ? (unsigned)E1c : (offs[NB0 + B + 1] - (unsigned)E0c);
    int n = (int)(end - beg);
    if (n > CAP) n = CAP;
    if (tid < DB1) cur_s[tid] = 0u;
    __syncthreads();
    for (int i = tid; i < n; i += 256) {
        int dl = (coarse1[beg + i] >> 17) & 63;
        atomicAdd(&cur_s[dl], 1u);
    }
    __syncthreads();
    if (tid == 0) {
        unsigned a = 0;
        for (int i = 0; i < DB1; i++) { unsigned c = cur_s[i]; off_s[i] = a; a += c; }
        off_s[DB1] = a;
    }
    __syncthreads();
    if (tid < DB1) cur_s[tid] = off_s[tid];
    __syncthreads();
    for (int i = tid; i < n; i += 256) {
        int dl = (coarse1[beg + i] >> 17) & 63;
        unsigned slot = atomicAdd(&cur_s[dl], 1u);
        eidx[slot] = (unsigned short)i;
    }
    __syncthreads();
    int wav = tid >> 6, lane = tid & 63, q = lane >> 5, l = lane & 31, h = l >> 3;
    const float NEG = -3.0e38f;
    for (int dl = wav; dl < nd; dl += 4) {
        int rbeg = (int)off_s[dl], rend = (int)off_s[dl + 1];
        bool single = (rend - rbeg) <= 64;
        float4 mx = {NEG, NEG, NEG, NEG};
        int s_reg = 0;
        float4 sc_reg = {NEG, NEG, NEG, NEG};
        // pass A: per-head max
        for (int base = rbeg; base < rend; base += 64) {
            int m = min(64, rend - base);
            int s = 0;
            float4 sc = {NEG, NEG, NEG, NEG};
            if (lane < m) {
                s = coarse1[beg + eidx[base + lane]] & 0x1FFFF;
                sc = ((const float4*)score)[s];
            }
            if (single) { s_reg = s; sc_reg = sc; }
            mx.x = fmaxf(mx.x, sc.x); mx.y = fmaxf(mx.y, sc.y);
            mx.z = fmaxf(mx.z, sc.z); mx.w = fmaxf(mx.w, sc.w);
        }
#pragma unroll
        for (int o = 1; o < 64; o <<= 1) {
            mx.x = fmaxf(mx.x, __shfl_xor(mx.x, o));
            mx.y = fmaxf(mx.y, __shfl_xor(mx.y, o));
            mx.z = fmaxf(mx.z, __shfl_xor(mx.z, o));
            mx.w = fmaxf(mx.w, __shfl_xor(mx.w, o));
        }
        float mh = h == 0 ? mx.x : h == 1 ? mx.y : h == 2 ? mx.z : mx.w;
        float4 acc = {0.f, 0.f, 0.f, 0.f};
        float sex = 0.f;
        // pass B: acc += exp(score-max) * feat, 2 edges in flight
        for (int base = rbeg; base < rend; base += 64) {
            int m = min(64, rend - base);
            int s;
            float4 sc;
            if (single) {
                s = s_reg; sc = sc_reg;
            } else {
                s = 0; sc.x = sc.y = sc.z = sc.w = NEG;
                if (lane < m) {
                    s = coarse1[beg + eidx[base + lane]] & 0x1FFFF;
                    sc = ((const float4*)score)[s];
                }
            }
            int rounds = (m + 1) >> 1;
            for (int t = 0; t < rounds; t++) {
                int idx = 2 * t + q;
                int sj = __shfl(s, idx);
                float sx = __shfl(sc.x, idx), sy = __shfl(sc.y, idx);
                float sz = __shfl(sc.z, idx), sw = __shfl(sc.w, idx);
                float sch = h == 0 ? sx : h == 1 ? sy : h == 2 ? sz : sw;
                float ex = __expf(sch - mh);
                float4 v = ((const float4*)(feat + (size_t)sj * 128))[l];
                acc.x += v.x * ex; acc.y += v.y * ex;
                acc.z += v.z * ex; acc.w += v.w * ex;
                sex += ex;
            }
        }
        acc.x += __shfl_xor(acc.x, 32); acc.y += __shfl_xor(acc.y, 32);
        acc.z += __shfl_xor(acc.z, 32); acc.w += __shfl_xor(acc.w, 32);
        sex += __shfl_xor(sex, 32);
        float inv = 1.f / sex;
        acc.x *= inv; acc.y *= inv; acc.z *= inv; acc.w *= inv;
        acc.x += __shfl_xor(acc.x, 8);  acc.y += __shfl_xor(acc.y, 8);
        acc.z += __shfl_xor(acc.z, 8);  acc.w += __shfl_xor(acc.w, 8);
        acc.x += __shfl_xor(acc.x, 16); acc.y += __shfl_xor(acc.y, 16);
        acc.z += __shfl_xor(acc.z, 16); acc.w += __shfl_xor(acc.w, 16);
        if (lane < 8) ((float4*)(out + (size_t)(d0 + dl) * 32))[lane] = acc;
    }
}

extern "C" void kernel_launch(void* const* d_in, const int* in_sizes, int n_in,
                              void* d_out, int out_size, void* d_ws, size_t ws_size,
                              hipStream_t stream) {
    const float* x      = (const float*)d_in[0];
    const float* norm_n = (const float*)d_in[1];
    const float* norm_e = (const float*)d_in[2];
    const float* W1     = (const float*)d_in[3];
    const float* b1     = (const float*)d_in[4];
    const float* Wsrc   = (const float*)d_in[5];
    const float* bsrc   = (const float*)d_in[6];
    const float* attn   = (const float*)d_in[7];
    const int* src0     = (const int*)d_in[8];
    const int* dst0     = (const int*)d_in[9];
    const int* node_graph = (const int*)d_in[10];
    const int* src1     = (const int*)d_in[11];
    const int* dst1     = (const int*)d_in[12];
    float* out = (float*)d_out;

    char* ws = (char*)d_ws;
    size_t off = 0;
    auto alloc = [&](size_t bytes) {
        void* p = ws + off;
        off += (bytes + 255) & ~(size_t)255;   // keep 16B+ alignment for float4
        return p;
    };

    unsigned* cnt  = (unsigned*)alloc(NBk * 4);         // zeroed
    unsigned* cntN = (unsigned*)alloc((size_t)Rc * 4);  // zeroed
    size_t zero_bytes = off;
    unsigned* offs = (unsigned*)alloc(NBk * 4);
    unsigned* gcur = (unsigned*)alloc(NBk * 4);
    unsigned* bsum = (unsigned*)alloc(1024 * 4);
    // region A: coarse0 (16 MB) then feat (51.2 MB) — coarse0 dead before k_mlp writes feat
    char* pA = (char*)alloc((size_t)Rc * 128 * 4);
    int2* coarse0 = (int2*)pA;
    float* feat   = (float*)pA;
    int* coarse1  = (int*)alloc((size_t)E1c * 4);
    float* r_mean = (float*)alloc((size_t)Rc * 64 * 4);
    float* score_src = (float*)alloc((size_t)Rc * 4 * 4);

    hipMemsetAsync(d_ws, 0, zero_bytes, stream);

    k_hist_coarse<<<PB, 256, 0, stream>>>(dst0, node_graph, dst1, cnt, cntN);
    int nb = (NBk + 1023) / 1024;   // 3
    k_scan1<<<nb, 1024, 0, stream>>>(cnt, offs, bsum, NBk);
    k_scan2<<<1, 1024, 0, stream>>>(bsum, nb);
    k_scan3<<<nb, 1024, 0, stream>>>(offs, bsum, gcur, NBk);

    k_place_coarse<<<PB, 256, 0, stream>>>(src0, dst0, node_graph, norm_n, norm_e,
                                           src1, dst1, gcur, coarse0, coarse1);

    k_bucket0<<<NB0, 256, 0, stream>>>(x, coarse0, offs, cntN, r_mean);
    k_mlp<<<Rc / MTILE, 512, 0, stream>>>(r_mean, W1, b1, Wsrc, bsrc, attn, feat, score_src, Rc);
    k_bucket1<<<NB1, 256, 0, stream>>>(feat, score_src, coarse1, offs, out);
}